// Round 1
// baseline (1330.827 us; speedup 1.0000x reference)
//
#include <hip/hip_runtime.h>
#include <hip/hip_bf16.h>
#include <math.h>

#define B_   8
#define C_   128
#define H_   64
#define W_   64
#define E_   8
#define HW_  4096
#define K9_  1152   // 128*9

// ---------------- channel means: x0[b*128+c] = mean_hw x[b][c] ----------------
__global__ __launch_bounds__(256) void k_mean(const float* __restrict__ x,
                                              float* __restrict__ x0) {
  int bc = blockIdx.x;  // b*128 + c  (1024 blocks)
  const float4* p = (const float4*)(x + (size_t)bc * HW_);
  float s = 0.f;
  for (int i = threadIdx.x; i < HW_ / 4; i += 256) {
    float4 v = p[i];
    s += v.x + v.y + v.z + v.w;
  }
#pragma unroll
  for (int off = 32; off > 0; off >>= 1) s += __shfl_down(s, off);
  __shared__ float red[4];
  if ((threadIdx.x & 63) == 0) red[threadIdx.x >> 6] = s;
  __syncthreads();
  if (threadIdx.x == 0)
    x0[bc] = (red[0] + red[1] + red[2] + red[3]) * (1.f / HW_);
}

// ---------------- gates: softmax, top2, weights, needed mask, loss ----------------
__global__ __launch_bounds__(256) void k_gate(const float* __restrict__ x0,
    const float* __restrict__ g1, const float* __restrict__ g2,
    const float* __restrict__ g3, const float* __restrict__ g4,
    float* __restrict__ wmat, float* __restrict__ w2, int* __restrict__ idxb,
    int* __restrict__ needed, float* __restrict__ lossp) {
  __shared__ float go[4][8][8];
  int t = threadIdx.x;
  int g = t >> 6, b = (t >> 3) & 7, e = t & 7;
  const float* gp = (g == 0) ? g1 : (g == 1) ? g2 : (g == 2) ? g3 : g4;
  const float* xr = x0 + b * C_;
  float s = 0.f;
  for (int c = 0; c < C_; ++c) s += xr[c] * gp[c * E_ + e];
  go[g][b][e] = s;            // logits for now
  wmat[t] = 0.f;
  if (t < 64) needed[t] = 0;
  __syncthreads();
  if (t < 32) {
    int gg = t >> 3, bb = t & 7;
    float m = -1e30f;
#pragma unroll
    for (int k = 0; k < 8; ++k) m = fmaxf(m, go[gg][bb][k]);
    float tmp[8];
    float sum = 0.f;
#pragma unroll
    for (int k = 0; k < 8; ++k) { tmp[k] = expf(go[gg][bb][k] - m); sum += tmp[k]; }
    float inv = 1.f / sum;
#pragma unroll
    for (int k = 0; k < 8; ++k) { tmp[k] *= inv; go[gg][bb][k] = tmp[k]; }
    // top-2 (lax.top_k tie-break: first index wins)
    float v0 = -1.f; int i0 = 0;
#pragma unroll
    for (int k = 0; k < 8; ++k) if (tmp[k] > v0) { v0 = tmp[k]; i0 = k; }
    float v1 = -1.f; int i1 = 0;
#pragma unroll
    for (int k = 0; k < 8; ++k) if (k != i0 && tmp[k] > v1) { v1 = tmp[k]; i1 = k; }
    float e1 = expf(v1 - v0);
    float w0 = 1.f / (1.f + e1), w1 = e1 / (1.f + e1);
    w2[t * 2] = w0; w2[t * 2 + 1] = w1;
    idxb[t * 2] = i0; idxb[t * 2 + 1] = i1;
    wmat[(gg * 8 + bb) * 8 + i0] = w0;
    wmat[(gg * 8 + bb) * 8 + i1] = w1;
    needed[i0 * 8 + bb] = 1;   // benign same-value races
    needed[i1 * 8 + bb] = 1;
  }
  __syncthreads();
  if (t == 0) {
    float total = 0.f;
    for (int gg = 0; gg < 4; ++gg) {
      float us[8]; float mean = 0.f;
      for (int k = 0; k < 8; ++k) {
        float u = 0.f;
        for (int bb = 0; bb < 8; ++bb) u += go[gg][bb][k];
        us[k] = u; mean += u;
      }
      mean *= 0.125f;
      float var = 0.f;
      for (int k = 0; k < 8; ++k) { float d = us[k] - mean; var += d * d; }
      var *= (1.f / 7.f);
      total += var / (mean * mean + 1e-10f);
    }
    *lossp = total;
  }
}

// ---------------- weight transpose: Wt[e][k][co], Pt[e][ci][co] ----------------
__global__ __launch_bounds__(256) void k_tr(const float* __restrict__ Wc,
                                            const float* __restrict__ Wp,
                                            float* __restrict__ Wt,
                                            float* __restrict__ Pt) {
  int tid = blockIdx.x * blockDim.x + threadIdx.x;
  int stride = gridDim.x * blockDim.x;
  const int n1 = E_ * K9_ * C_;   // 1179648
  for (int i = tid; i < n1; i += stride) {
    int e = i / (K9_ * C_);
    int r = i - e * (K9_ * C_);
    int k = r >> 7, co = r & 127;
    Wt[i] = Wc[((size_t)(e * C_ + co)) * K9_ + k];
  }
  const int n2 = E_ * C_ * C_;    // 131072
  for (int i = tid; i < n2; i += stride) {
    int e = i >> 14;
    int r = i & 16383;
    int ci = r >> 7, co = r & 127;
    Pt[i] = Wp[((e * C_ + co) << 7) + ci];
  }
}

// ---------------- fused expert: conv3x3 + squash + 1x1 proj ----------------
// grid (16 tiles, 8 b, 8 e), 512 threads.  Tile = 16x16 positions, M = 128 co.
// Thread tile 8co x 8pos (64 f32 acc).  LDS: A=128KB (im2col|part|v), B=18KB (W chunks)
__global__ __launch_bounds__(512, 2) void k_expert(
    const float* __restrict__ x, const float* __restrict__ Wt,
    const float* __restrict__ Pt, const float* __restrict__ bcap,
    const float* __restrict__ bproj, const int* __restrict__ needed,
    const float* __restrict__ wmat, float* __restrict__ expb,
    float* __restrict__ yout, int use_exp) {
  int e = blockIdx.z, b = blockIdx.y;
  if (needed[e * 8 + b] == 0) return;
  int tile = blockIdx.x;
  int ty = (tile >> 2) * 16, tx = (tile & 3) * 16;

  __shared__ float A[32768];   // 128 KB
  __shared__ float Bb[4608];   // 18 KB
  float* xcol = A;             // [36][256] during conv
  float* part = A + 9216;      // [16][256] squash partials
  float* vbuf = A;             // [128][256] during proj

  int tid = threadIdx.x;
  int tm = tid >> 5, tn = tid & 31;
  int co0 = tm * 8, p0 = tn * 8;

  float acc[8][8];
#pragma unroll
  for (int i = 0; i < 8; ++i)
#pragma unroll
    for (int j = 0; j < 8; ++j) acc[i][j] = 0.f;

  const float* xb = x + (size_t)b * C_ * HW_;
  const float* wte = Wt + (size_t)e * K9_ * C_;

  for (int ci0 = 0; ci0 < C_; ci0 += 4) {
    // stage transposed-weight chunk [36][128]
    {
      const float4* src = (const float4*)(wte + (size_t)ci0 * 9 * C_);
      float4* dst = (float4*)Bb;
      for (int i = tid; i < 36 * 128 / 4; i += 512) dst[i] = src[i];
    }
    // build im2col chunk [36][256]
    for (int i = tid; i < 36 * 256; i += 512) {
      int k = i >> 8, p = i & 255;
      int ci = k / 9;
      int r = k - ci * 9;
      int ky = r / 3;
      int kx = r - ky * 3;
      int py = p >> 4, px = p & 15;
      int gy = ty + py + ky - 1;
      int gx = tx + px + kx - 1;
      float v = 0.f;
      if ((unsigned)gy < 64u && (unsigned)gx < 64u)
        v = xb[(size_t)(ci0 + ci) * HW_ + gy * 64 + gx];
      xcol[i] = v;
    }
    __syncthreads();
#pragma unroll 4
    for (int k = 0; k < 36; ++k) {
      float4 wA = *(const float4*)&Bb[k * 128 + co0];
      float4 wB = *(const float4*)&Bb[k * 128 + co0 + 4];
      float4 xA = *(const float4*)&xcol[k * 256 + p0];
      float4 xB = *(const float4*)&xcol[k * 256 + p0 + 4];
      float wr[8] = {wA.x, wA.y, wA.z, wA.w, wB.x, wB.y, wB.z, wB.w};
      float xr[8] = {xA.x, xA.y, xA.z, xA.w, xB.x, xB.y, xB.z, xB.w};
#pragma unroll
      for (int i = 0; i < 8; ++i)
#pragma unroll
        for (int j = 0; j < 8; ++j)
          acc[i][j] = fmaf(wr[i], xr[j], acc[i][j]);
    }
    __syncthreads();
  }

  // + caps bias, then squash partial sums
  float bcr[8];
#pragma unroll
  for (int i = 0; i < 8; ++i) bcr[i] = bcap[e * C_ + co0 + i];
#pragma unroll
  for (int i = 0; i < 8; ++i)
#pragma unroll
    for (int j = 0; j < 8; ++j) acc[i][j] += bcr[i];

#pragma unroll
  for (int j = 0; j < 8; ++j) {
    float ps = 0.f;
#pragma unroll
    for (int i = 0; i < 8; ++i) ps += acc[i][j] * acc[i][j];
    part[tm * 256 + p0 + j] = ps;
  }
  __syncthreads();
  float f[8];
#pragma unroll
  for (int j = 0; j < 8; ++j) {
    float sn = 0.f;
    for (int t2 = 0; t2 < 16; ++t2) sn += part[t2 * 256 + p0 + j];
    f[j] = sn / ((1.f + sn) * (sqrtf(sn) + 1e-8f));   // sn/(1+sn) * 1/(sqrt(sn)+eps)
  }
  __syncthreads();   // all part reads done before vbuf overwrites A
  // v = u * f  -> LDS [128][256]
#pragma unroll
  for (int i = 0; i < 8; ++i) {
    float4 v0 = {acc[i][0] * f[0], acc[i][1] * f[1], acc[i][2] * f[2], acc[i][3] * f[3]};
    float4 v1 = {acc[i][4] * f[4], acc[i][5] * f[5], acc[i][6] * f[6], acc[i][7] * f[7]};
    *(float4*)&vbuf[(co0 + i) * 256 + p0] = v0;
    *(float4*)&vbuf[(co0 + i) * 256 + p0 + 4] = v1;
  }
  __syncthreads();

  // 1x1 proj GEMM: K=128 in chunks of 32
#pragma unroll
  for (int i = 0; i < 8; ++i)
#pragma unroll
    for (int j = 0; j < 8; ++j) acc[i][j] = 0.f;
  const float* pte = Pt + (size_t)e * C_ * C_;
  for (int c0 = 0; c0 < C_; c0 += 32) {
    {
      const float4* src = (const float4*)(pte + (size_t)c0 * C_);
      float4* dst = (float4*)Bb;
      for (int i = tid; i < 32 * 128 / 4; i += 512) dst[i] = src[i];
    }
    __syncthreads();
#pragma unroll 4
    for (int k = 0; k < 32; ++k) {
      float4 wA = *(const float4*)&Bb[k * 128 + co0];
      float4 wB = *(const float4*)&Bb[k * 128 + co0 + 4];
      float4 xA = *(const float4*)&vbuf[(c0 + k) * 256 + p0];
      float4 xB = *(const float4*)&vbuf[(c0 + k) * 256 + p0 + 4];
      float wr[8] = {wA.x, wA.y, wA.z, wA.w, wB.x, wB.y, wB.z, wB.w};
      float xr[8] = {xA.x, xA.y, xA.z, xA.w, xB.x, xB.y, xB.z, xB.w};
#pragma unroll
      for (int i = 0; i < 8; ++i)
#pragma unroll
        for (int j = 0; j < 8; ++j)
          acc[i][j] = fmaf(wr[i], xr[j], acc[i][j]);
    }
    __syncthreads();
  }

  float bpr[8];
#pragma unroll
  for (int i = 0; i < 8; ++i) bpr[i] = bproj[e * C_ + co0 + i];
  int py = tn >> 1, px = (tn & 1) * 8;

  if (use_exp) {
    float* op = expb + (size_t)((e * 8 + b) * C_ + co0) * HW_ +
                (size_t)(ty + py) * 64 + tx + px;
#pragma unroll
    for (int i = 0; i < 8; ++i) {
      float4 r0 = {acc[i][0] + bpr[i], acc[i][1] + bpr[i], acc[i][2] + bpr[i], acc[i][3] + bpr[i]};
      float4 r1 = {acc[i][4] + bpr[i], acc[i][5] + bpr[i], acc[i][6] + bpr[i], acc[i][7] + bpr[i]};
      *(float4*)(op + (size_t)i * HW_) = r0;
      *(float4*)(op + (size_t)i * HW_ + 4) = r1;
    }
  } else {
    // fallback: atomic accumulate directly into the 4 gate outputs
    for (int g = 0; g < 4; ++g) {
      float w = wmat[(g * 8 + b) * 8 + e];
      if (w != 0.f) {
        float* op = yout + (size_t)(g * 8 + b) * (C_ * HW_) + (size_t)co0 * HW_ +
                    (size_t)(ty + py) * 64 + tx + px;
#pragma unroll
        for (int i = 0; i < 8; ++i)
#pragma unroll
          for (int j = 0; j < 8; ++j)
            atomicAdd(op + (size_t)i * HW_ + j, w * (acc[i][j] + bpr[i]));
      }
    }
  }
}

// ---------------- combine: y[g][b] = w0*exp[i0][b] + w1*exp[i1][b] ----------------
__global__ __launch_bounds__(256) void k_combine(const float* __restrict__ expb,
    const int* __restrict__ idxb, const float* __restrict__ w2,
    float* __restrict__ yout) {
  int gb = blockIdx.y;     // g*8+b
  int b = gb & 7;
  int i0 = idxb[gb * 2], i1 = idxb[gb * 2 + 1];
  float w0 = w2[gb * 2], w1 = w2[gb * 2 + 1];
  const float4* p0 = (const float4*)(expb + (size_t)(i0 * 8 + b) * (C_ * HW_));
  const float4* p1 = (const float4*)(expb + (size_t)(i1 * 8 + b) * (C_ * HW_));
  float4* o = (float4*)(yout + (size_t)gb * (C_ * HW_));
  for (int i = blockIdx.x * 256 + threadIdx.x; i < C_ * HW_ / 4;
       i += gridDim.x * 256) {
    float4 a = p0[i], c = p1[i];
    float4 r = {w0 * a.x + w1 * c.x, w0 * a.y + w1 * c.y,
                w0 * a.z + w1 * c.z, w0 * a.w + w1 * c.w};
    o[i] = r;
  }
}

extern "C" void kernel_launch(void* const* d_in, const int* in_sizes, int n_in,
                              void* d_out, int out_size, void* d_ws, size_t ws_size,
                              hipStream_t stream) {
  const float* x  = (const float*)d_in[0];
  const float* g1 = (const float*)d_in[1];
  const float* g2 = (const float*)d_in[2];
  const float* g3 = (const float*)d_in[3];
  const float* g4 = (const float*)d_in[4];
  const float* Wc = (const float*)d_in[5];
  const float* bc = (const float*)d_in[6];
  const float* Wp = (const float*)d_in[7];
  const float* bp = (const float*)d_in[8];
  float* out = (float*)d_out;

  const size_t EXPF = (size_t)E_ * B_ * C_ * HW_;   // 33,554,432 floats (134 MB)
  const size_t WTF  = (size_t)E_ * K9_ * C_;        // 1,179,648
  const size_t PTF  = (size_t)E_ * C_ * C_;         // 131,072
  const size_t smallF = WTF + PTF + 1024 + 256 + 64;
  const size_t needB  = (EXPF + smallF) * 4 + 64 * 4 * 2 + 1024;
  int use_exp = (ws_size >= needB) ? 1 : 0;

  char* p = (char*)d_ws;
  float* expb = nullptr;
  if (use_exp) { expb = (float*)p; p += EXPF * 4; }
  float* Wt   = (float*)p; p += WTF * 4;
  float* Pt   = (float*)p; p += PTF * 4;
  float* x0   = (float*)p; p += 1024 * 4;
  float* wmat = (float*)p; p += 256 * 4;
  float* w2   = (float*)p; p += 64 * 4;
  int*   idxb = (int*)p;   p += 64 * 4;
  int*   needed = (int*)p; p += 64 * 4;

  if (!use_exp)
    hipMemsetAsync(d_out, 0, (size_t)4 * B_ * C_ * HW_ * 4, stream);

  k_mean<<<dim3(B_ * C_), dim3(256), 0, stream>>>(x, x0);
  k_gate<<<dim3(1), dim3(256), 0, stream>>>(x0, g1, g2, g3, g4, wmat, w2, idxb,
                                            needed, out + (size_t)4 * B_ * C_ * HW_);
  k_tr<<<dim3(1024), dim3(256), 0, stream>>>(Wc, Wp, Wt, Pt);
  k_expert<<<dim3(16, B_, E_), dim3(512), 0, stream>>>(x, Wt, Pt, bc, bp, needed,
                                                       wmat, expb, out, use_exp);
  if (use_exp)
    k_combine<<<dim3(64, 32), dim3(256), 0, stream>>>(expb, idxb, w2, out);
}

// Round 2
// 304.040 us; speedup vs baseline: 4.3771x; 4.3771x over previous
//
#include <hip/hip_runtime.h>
#include <math.h>

#define B_   8
#define C_   128
#define E_   8
#define HW_  4096

typedef unsigned short u16;
typedef unsigned int   u32;
typedef __attribute__((ext_vector_type(8))) short bf16x8;
typedef __attribute__((ext_vector_type(4))) float f32x4;

__device__ __forceinline__ u16 f2bf(float f) {
  u32 u = __float_as_uint(f);
  u32 r = (u + 0x7fffu + ((u >> 16) & 1u)) >> 16;
  return (u16)r;
}
__device__ __forceinline__ float bf2f(u16 h) {
  return __uint_as_float(((u32)h) << 16);
}
__device__ __forceinline__ void gld_lds16(const u16* g, u16* l) {
  __builtin_amdgcn_global_load_lds((const __attribute__((address_space(1))) u32*)g,
                                   (__attribute__((address_space(3))) u32*)(void*)l,
                                   16, 0, 0);
}
#define MFMA(a, b, c) __builtin_amdgcn_mfma_f32_16x16x32_bf16(a, b, c, 0, 0, 0)

// ---------------- channel means ----------------
__global__ __launch_bounds__(256) void k_mean(const float* __restrict__ x,
                                              float* __restrict__ x0) {
  int bc = blockIdx.x;
  const float4* p = (const float4*)(x + (size_t)bc * HW_);
  float s = 0.f;
  for (int i = threadIdx.x; i < HW_ / 4; i += 256) {
    float4 v = p[i];
    s += v.x + v.y + v.z + v.w;
  }
#pragma unroll
  for (int off = 32; off > 0; off >>= 1) s += __shfl_down(s, off);
  __shared__ float red[4];
  if ((threadIdx.x & 63) == 0) red[threadIdx.x >> 6] = s;
  __syncthreads();
  if (threadIdx.x == 0)
    x0[bc] = (red[0] + red[1] + red[2] + red[3]) * (1.f / HW_);
}

// ---------------- gates ----------------
__global__ __launch_bounds__(256) void k_gate(const float* __restrict__ x0,
    const float* __restrict__ g1, const float* __restrict__ g2,
    const float* __restrict__ g3, const float* __restrict__ g4,
    float* __restrict__ wmat, float* __restrict__ w2, int* __restrict__ idxb,
    int* __restrict__ needed, float* __restrict__ lossp) {
  __shared__ float go[4][8][8];
  int t = threadIdx.x;
  int g = t >> 6, b = (t >> 3) & 7, e = t & 7;
  const float* gp = (g == 0) ? g1 : (g == 1) ? g2 : (g == 2) ? g3 : g4;
  const float* xr = x0 + b * C_;
  float s = 0.f;
  for (int c = 0; c < C_; ++c) s += xr[c] * gp[c * E_ + e];
  go[g][b][e] = s;
  wmat[t] = 0.f;
  if (t < 64) needed[t] = 0;
  __syncthreads();
  if (t < 32) {
    int gg = t >> 3, bb = t & 7;
    float m = -1e30f;
#pragma unroll
    for (int k = 0; k < 8; ++k) m = fmaxf(m, go[gg][bb][k]);
    float tmp[8]; float sum = 0.f;
#pragma unroll
    for (int k = 0; k < 8; ++k) { tmp[k] = expf(go[gg][bb][k] - m); sum += tmp[k]; }
    float inv = 1.f / sum;
#pragma unroll
    for (int k = 0; k < 8; ++k) { tmp[k] *= inv; go[gg][bb][k] = tmp[k]; }
    float v0 = -1.f; int i0 = 0;
#pragma unroll
    for (int k = 0; k < 8; ++k) if (tmp[k] > v0) { v0 = tmp[k]; i0 = k; }
    float v1 = -1.f; int i1 = 0;
#pragma unroll
    for (int k = 0; k < 8; ++k) if (k != i0 && tmp[k] > v1) { v1 = tmp[k]; i1 = k; }
    float e1 = expf(v1 - v0);
    float w0 = 1.f / (1.f + e1), w1 = e1 / (1.f + e1);
    w2[t * 2] = w0; w2[t * 2 + 1] = w1;
    idxb[t * 2] = i0; idxb[t * 2 + 1] = i1;
    wmat[(gg * 8 + bb) * 8 + i0] = w0;
    wmat[(gg * 8 + bb) * 8 + i1] = w1;
    needed[i0 * 8 + bb] = 1;
    needed[i1 * 8 + bb] = 1;
  }
  __syncthreads();
  if (t == 0) {
    float total = 0.f;
    for (int gg = 0; gg < 4; ++gg) {
      float us[8]; float mean = 0.f;
      for (int k = 0; k < 8; ++k) {
        float u = 0.f;
        for (int bb = 0; bb < 8; ++bb) u += go[gg][bb][k];
        us[k] = u; mean += u;
      }
      mean *= 0.125f;
      float var = 0.f;
      for (int k = 0; k < 8; ++k) { float d = us[k] - mean; var += d * d; }
      var *= (1.f / 7.f);
      total += var / (mean * mean + 1e-10f);
    }
    *lossp = total;
  }
}

// ---------------- prep X: f32 [b][ci][hw] -> bf16 hi/lo [b][hw][ci] ----------------
__global__ __launch_bounds__(256) void k_prepx(const float* __restrict__ x,
                                               u16* __restrict__ XTh,
                                               u16* __restrict__ XTl) {
  int y = blockIdx.x;   // row 0..63
  int b = blockIdx.y;
  __shared__ float T[64 * 129];
  for (int i = threadIdx.x; i < 128 * 64; i += 256) {
    int ci = i >> 6, xc = i & 63;
    T[xc * 129 + ci] = x[((size_t)(b * 128 + ci)) * HW_ + y * 64 + xc];
  }
  __syncthreads();
  for (int i = threadIdx.x; i < 64 * 128; i += 256) {
    int xc = i >> 7, ci = i & 127;
    float v = T[xc * 129 + ci];
    u16 h = f2bf(v);
    size_t o = ((size_t)(b * HW_ + y * 64 + xc)) * 128 + ci;
    XTh[o] = h;
    XTl[o] = f2bf(v - bf2f(h));
  }
}

// ---------------- prep W: pre-swizzled bf16 hi/lo tiles ----------------
// conv: Wph/Wpl [e][tap 9][chunk 2][tile 8192 u16]  tile idx = co*64 + (k ^ ((co&7)<<3))
// proj: Pph/Ppl [e][chunk 4][tile 4096 u16]        tile idx = co*32 + (k ^ ((co&3)<<3))
__global__ __launch_bounds__(256) void k_prepw(const float* __restrict__ Wc,
    const float* __restrict__ Wp, u16* __restrict__ Wph, u16* __restrict__ Wpl,
    u16* __restrict__ Pph, u16* __restrict__ Ppl) {
  int gid = blockIdx.x * 256 + threadIdx.x;
  int stride = gridDim.x * 256;
  const int N1 = 8 * 9 * 2 * 128 * 64;
  for (int g = gid; g < N1; g += stride) {
    int k = g & 63;
    int co = (g >> 6) & 127;
    int ch = (g >> 13) & 1;
    int v = g >> 14;            // e*9 + tap
    int tap = v % 9, e = v / 9;
    int ci = ch * 64 + k;
    float wv = Wc[(((size_t)(e * 128 + co)) * 128 + ci) * 9 + tap];
    u16 h = f2bf(wv), lo = f2bf(wv - bf2f(h));
    int idx = (v * 2 + ch) * 8192 + co * 64 + (k ^ ((co & 7) << 3));
    Wph[idx] = h; Wpl[idx] = lo;
  }
  const int N2 = 8 * 4 * 128 * 32;
  for (int g = gid; g < N2; g += stride) {
    int k = g & 31;
    int co = (g >> 5) & 127;
    int c = (g >> 12) & 3;
    int e = g >> 14;
    int ci = c * 32 + k;
    float wv = Wp[((size_t)(e * 128 + co)) * 128 + ci];
    u16 h = f2bf(wv), lo = f2bf(wv - bf2f(h));
    int idx = (e * 4 + c) * 4096 + co * 32 + (k ^ ((co & 3) << 3));
    Pph[idx] = h; Ppl[idx] = lo;
  }
}

// ---------------- fused expert via MFMA (bf16x3 split) ----------------
// grid (32 pos-tiles, b, e), 256 threads = 4 waves (2co x 2n of 64x64).
// K-stage = (tap, ci-chunk 64): stage Ah,Al (global_load_lds, pre-swizzled) +
// Bh,Bl (reg->LDS, XOR swizzle), then 96 MFMA/wave.  Then squash + 1x1 proj MFMA.
__global__ __launch_bounds__(256, 2) void k_expert(
    const u16* __restrict__ XTh, const u16* __restrict__ XTl,
    const u16* __restrict__ Wph, const u16* __restrict__ Wpl,
    const u16* __restrict__ Pph, const u16* __restrict__ Ppl,
    const float* __restrict__ bcap, const float* __restrict__ bproj,
    const int* __restrict__ needed, const float* __restrict__ wmat,
    float* __restrict__ expb, float* __restrict__ yout, int use_exp) {
  int e = blockIdx.z, b = blockIdx.y;
  if (!needed[e * 8 + b]) return;
  int tile = blockIdx.x;
  int y0 = tile * 2;

  __shared__ __align__(16) char smem[75264];
  u16* S = (u16*)smem;
  const int Ah = 0, Al = 8192, Bh = 16384, Bl = 24576;   // u16 offsets, 16KB tiles
  const int Vh = 0, Vl = 16384, Pt = 32768;               // proj phase reuse
  float* snb = (float*)(smem + 73728);  // [2][128]
  float* fb  = (float*)(smem + 74752);  // [128]

  int tid = threadIdx.x;
  int lane = tid & 63, w = tid >> 6;
  int l15 = lane & 15, l4 = lane >> 4;
  int cob = (w >> 1) * 64, nb = (w & 1) * 64;

  f32x4 zero4 = {0.f, 0.f, 0.f, 0.f};
  f32x4 acc[4][4];
#pragma unroll
  for (int i = 0; i < 4; ++i)
#pragma unroll
    for (int j = 0; j < 4; ++j) acc[i][j] = zero4;

  // B-staging coords: thread -> (n, half of k-groups)
  int sn_ = tid >> 1;            // n 0..127
  int kh = (tid & 1) * 4;
  int srow = y0 + (sn_ >> 6);
  int scol = sn_ & 63;

  for (int tap = 0; tap < 9; ++tap) {
    int dy = tap / 3 - 1, dx = tap % 3 - 1;
    int row = srow + dy, col = scol + dx;
    bool val = ((unsigned)row < 64u) && ((unsigned)col < 64u);
    int gidx = val ? ((b * HW_ + row * 64 + col) * 128) : 0;
    for (int ch = 0; ch < 2; ++ch) {
      __syncthreads();   // prior MFMA reads complete before overwrite
      const u16* wsh = Wph + (size_t)(((e * 9 + tap) * 2 + ch)) * 8192;
      const u16* wsl = Wpl + (size_t)(((e * 9 + tap) * 2 + ch)) * 8192;
#pragma unroll
      for (int q = 0; q < 4; ++q) {
        int off = (w * 4 + q) * 512;
        gld_lds16(wsh + off + lane * 8, S + Ah + off);
        gld_lds16(wsl + off + lane * 8, S + Al + off);
      }
      int ci0 = ch * 64;
#pragma unroll
      for (int i = 0; i < 4; ++i) {
        int kg = kh + i;
        uint4 vh4 = {0u, 0u, 0u, 0u}, vl4 = {0u, 0u, 0u, 0u};
        if (val) {
          vh4 = *(const uint4*)(XTh + gidx + ci0 + kg * 8);
          vl4 = *(const uint4*)(XTl + gidx + ci0 + kg * 8);
        }
        int wa = sn_ * 64 + ((kg * 8) ^ ((sn_ & 7) << 3));
        *(uint4*)(S + Bh + wa) = vh4;
        *(uint4*)(S + Bl + wa) = vl4;
      }
      __syncthreads();
#pragma unroll
      for (int ks = 0; ks < 2; ++ks) {
        bf16x8 fah[4], fal[4], fbh[4], fbl[4];
#pragma unroll
        for (int i = 0; i < 4; ++i) {
          int co = cob + i * 16 + l15;
          int ka = (ks * 32 + l4 * 8) ^ ((co & 7) << 3);
          fah[i] = *(const bf16x8*)(S + Ah + co * 64 + ka);
          fal[i] = *(const bf16x8*)(S + Al + co * 64 + ka);
        }
#pragma unroll
        for (int j = 0; j < 4; ++j) {
          int pn = nb + j * 16 + l15;
          int kb = (ks * 32 + l4 * 8) ^ ((pn & 7) << 3);
          fbh[j] = *(const bf16x8*)(S + Bh + pn * 64 + kb);
          fbl[j] = *(const bf16x8*)(S + Bl + pn * 64 + kb);
        }
#pragma unroll
        for (int i = 0; i < 4; ++i)
#pragma unroll
          for (int j = 0; j < 4; ++j) {
            acc[i][j] = MFMA(fah[i], fbh[j], acc[i][j]);
            acc[i][j] = MFMA(fah[i], fbl[j], acc[i][j]);
            acc[i][j] = MFMA(fal[i], fbh[j], acc[i][j]);
          }
      }
    }
  }

  // caps bias
#pragma unroll
  for (int i = 0; i < 4; ++i)
#pragma unroll
    for (int r = 0; r < 4; ++r) {
      float bc = bcap[e * 128 + cob + i * 16 + l4 * 4 + r];
#pragma unroll
      for (int j = 0; j < 4; ++j) acc[i][j][r] += bc;
    }

  // squash: sn per position (sum u^2 over all 128 co)
#pragma unroll
  for (int j = 0; j < 4; ++j) {
    float p = 0.f;
#pragma unroll
    for (int i = 0; i < 4; ++i)
#pragma unroll
      for (int r = 0; r < 4; ++r) p += acc[i][j][r] * acc[i][j][r];
    p += __shfl_xor(p, 16);
    p += __shfl_xor(p, 32);
    if (lane < 16) snb[(w >> 1) * 128 + nb + j * 16 + lane] = p;
  }
  __syncthreads();
  if (tid < 128) {
    float s2 = snb[tid] + snb[128 + tid];
    fb[tid] = s2 / ((1.f + s2) * (sqrtf(s2) + 1e-8f));
  }
  __syncthreads();

  // v = u*f -> LDS bf16 hi/lo [128 pos][128 ci], swizzled
#pragma unroll
  for (int j = 0; j < 4; ++j) {
    int pn = nb + j * 16 + l15;
    float fj = fb[pn];
#pragma unroll
    for (int i = 0; i < 4; ++i) {
      int co0v = cob + i * 16 + l4 * 4;
      float v0 = acc[i][j][0] * fj, v1 = acc[i][j][1] * fj;
      float v2 = acc[i][j][2] * fj, v3 = acc[i][j][3] * fj;
      u16 h0 = f2bf(v0), h1 = f2bf(v1), h2 = f2bf(v2), h3 = f2bf(v3);
      uint2 hp; hp.x = (u32)h0 | ((u32)h1 << 16); hp.y = (u32)h2 | ((u32)h3 << 16);
      u16 q0 = f2bf(v0 - bf2f(h0)), q1 = f2bf(v1 - bf2f(h1));
      u16 q2 = f2bf(v2 - bf2f(h2)), q3 = f2bf(v3 - bf2f(h3));
      uint2 lp; lp.x = (u32)q0 | ((u32)q1 << 16); lp.y = (u32)q2 | ((u32)q3 << 16);
      int ad = pn * 128 + (co0v ^ ((pn & 7) << 3));
      *(uint2*)(S + Vh + ad) = hp;
      *(uint2*)(S + Vl + ad) = lp;
    }
  }

  // 1x1 proj: y = P.v  (Ph.vh + Ph.vl + Pl.vh)
#pragma unroll
  for (int i = 0; i < 4; ++i)
#pragma unroll
    for (int j = 0; j < 4; ++j) acc[i][j] = zero4;

  for (int sp = 0; sp < 2; ++sp) {
    const u16* Psrc = sp ? Ppl : Pph;
    for (int c = 0; c < 4; ++c) {
      __syncthreads();
      const u16* ps = Psrc + (size_t)(e * 4 + c) * 4096;
#pragma unroll
      for (int q = 0; q < 2; ++q) {
        int off = (w * 2 + q) * 512;
        gld_lds16(ps + off + lane * 8, S + Pt + off);
      }
      __syncthreads();
      bf16x8 af[4], bvh[4], bvl[4];
#pragma unroll
      for (int i = 0; i < 4; ++i) {
        int co = cob + i * 16 + l15;
        int ka = (l4 * 8) ^ ((co & 3) << 3);
        af[i] = *(const bf16x8*)(S + Pt + co * 32 + ka);
      }
#pragma unroll
      for (int j = 0; j < 4; ++j) {
        int pn = nb + j * 16 + l15;
        int kb = (c * 32 + l4 * 8) ^ ((pn & 7) << 3);
        bvh[j] = *(const bf16x8*)(S + Vh + pn * 128 + kb);
        bvl[j] = *(const bf16x8*)(S + Vl + pn * 128 + kb);
      }
      if (sp == 0) {
#pragma unroll
        for (int i = 0; i < 4; ++i)
#pragma unroll
          for (int j = 0; j < 4; ++j) {
            acc[i][j] = MFMA(af[i], bvh[j], acc[i][j]);
            acc[i][j] = MFMA(af[i], bvl[j], acc[i][j]);
          }
      } else {
#pragma unroll
        for (int i = 0; i < 4; ++i)
#pragma unroll
          for (int j = 0; j < 4; ++j)
            acc[i][j] = MFMA(af[i], bvh[j], acc[i][j]);
      }
    }
  }

  // epilogue: + proj bias, store
  int posbase = tile * 128;
  if (use_exp) {
    float* ob = expb + ((size_t)((e * 8 + b) * 128)) * HW_;
#pragma unroll
    for (int i = 0; i < 4; ++i)
#pragma unroll
      for (int r = 0; r < 4; ++r) {
        int co = cob + i * 16 + l4 * 4 + r;
        float bp = bproj[e * 128 + co];
#pragma unroll
        for (int j = 0; j < 4; ++j) {
          int p = posbase + nb + j * 16 + l15;
          ob[(size_t)co * HW_ + p] = acc[i][j][r] + bp;
        }
      }
  } else {
    for (int g = 0; g < 4; ++g) {
      float wgt = wmat[(g * 8 + b) * 8 + e];
      if (wgt != 0.f) {
        float* ob = yout + (size_t)(g * 8 + b) * (C_ * HW_);
#pragma unroll
        for (int i = 0; i < 4; ++i)
#pragma unroll
          for (int r = 0; r < 4; ++r) {
            int co = cob + i * 16 + l4 * 4 + r;
            float bp = bproj[e * 128 + co];
#pragma unroll
            for (int j = 0; j < 4; ++j) {
              int p = posbase + nb + j * 16 + l15;
              atomicAdd(&ob[(size_t)co * HW_ + p], wgt * (acc[i][j][r] + bp));
            }
          }
      }
    }
  }
}

// ---------------- combine ----------------
__global__ __launch_bounds__(256) void k_combine(const float* __restrict__ expb,
    const int* __restrict__ idxb, const float* __restrict__ w2,
    float* __restrict__ yout) {
  int gb = blockIdx.y;
  int b = gb & 7;
  int i0 = idxb[gb * 2], i1 = idxb[gb * 2 + 1];
  float w0 = w2[gb * 2], w1 = w2[gb * 2 + 1];
  const float4* p0 = (const float4*)(expb + (size_t)(i0 * 8 + b) * (C_ * HW_));
  const float4* p1 = (const float4*)(expb + (size_t)(i1 * 8 + b) * (C_ * HW_));
  float4* o = (float4*)(yout + (size_t)gb * (C_ * HW_));
  for (int i = blockIdx.x * 256 + threadIdx.x; i < C_ * HW_ / 4;
       i += gridDim.x * 256) {
    float4 a = p0[i], c = p1[i];
    float4 r = {w0 * a.x + w1 * c.x, w0 * a.y + w1 * c.y,
                w0 * a.z + w1 * c.z, w0 * a.w + w1 * c.w};
    o[i] = r;
  }
}

extern "C" void kernel_launch(void* const* d_in, const int* in_sizes, int n_in,
                              void* d_out, int out_size, void* d_ws, size_t ws_size,
                              hipStream_t stream) {
  const float* x  = (const float*)d_in[0];
  const float* g1 = (const float*)d_in[1];
  const float* g2 = (const float*)d_in[2];
  const float* g3 = (const float*)d_in[3];
  const float* g4 = (const float*)d_in[4];
  const float* Wc = (const float*)d_in[5];
  const float* bc = (const float*)d_in[6];
  const float* Wp = (const float*)d_in[7];
  const float* bp = (const float*)d_in[8];
  float* out = (float*)d_out;

  const size_t EXPF = (size_t)E_ * B_ * C_ * HW_;   // 33.5M floats (134 MB)
  const size_t XTU  = (size_t)B_ * HW_ * C_;        // 4.19M u16 (8 MB) each
  const size_t WSU  = (size_t)8 * 9 * 2 * 8192;     // 1.18M u16 each
  const size_t PSU  = (size_t)8 * 4 * 4096;         // 131K u16 each
  const size_t needB = EXPF * 4 + 2 * XTU * 2 + 2 * WSU * 2 + 2 * PSU * 2 + 8192;
  int use_exp = (ws_size >= needB) ? 1 : 0;

  char* p = (char*)d_ws;
  float* expb = nullptr;
  if (use_exp) { expb = (float*)p; p += EXPF * 4; }
  u16* XTh = (u16*)p; p += XTU * 2;
  u16* XTl = (u16*)p; p += XTU * 2;
  u16* Wph = (u16*)p; p += WSU * 2;
  u16* Wpl = (u16*)p; p += WSU * 2;
  u16* Pph = (u16*)p; p += PSU * 2;
  u16* Ppl = (u16*)p; p += PSU * 2;
  float* x0   = (float*)p; p += 1024 * 4;
  float* wmat = (float*)p; p += 256 * 4;
  float* w2   = (float*)p; p += 64 * 4;
  int*   idxb = (int*)p;   p += 64 * 4;
  int*   needed = (int*)p; p += 64 * 4;

  if (!use_exp)
    hipMemsetAsync(d_out, 0, (size_t)4 * B_ * C_ * HW_ * 4, stream);

  k_mean<<<dim3(B_ * C_), dim3(256), 0, stream>>>(x, x0);
  k_gate<<<dim3(1), dim3(256), 0, stream>>>(x0, g1, g2, g3, g4, wmat, w2, idxb,
                                            needed, out + (size_t)4 * B_ * C_ * HW_);
  k_prepx<<<dim3(64, B_), dim3(256), 0, stream>>>(x, XTh, XTl);
  k_prepw<<<dim3(2048), dim3(256), 0, stream>>>(Wc, Wp, Wph, Wpl, Pph, Ppl);
  k_expert<<<dim3(32, B_, E_), dim3(256), 0, stream>>>(
      XTh, XTl, Wph, Wpl, Pph, Ppl, bc, bp, needed, wmat, expb, out, use_exp);
  if (use_exp)
    k_combine<<<dim3(64, 32), dim3(256), 0, stream>>>(expb, idxb, w2, out);
}